// Round 4
// baseline (2434.922 us; speedup 1.0000x reference)
//
#include <hip/hip_runtime.h>
#include <hip/hip_bf16.h>
#include <stdint.h>

#define B_ 4096
#define L_ 128
#define I_ 64
#define H_ 256
#define D_ 32
#define T_ 101
#define K_ 320   // I_+H_
#define NG 1024  // 4*H_

typedef __attribute__((ext_vector_type(8))) short short8;
typedef __attribute__((ext_vector_type(4))) float f32x4;

__device__ __forceinline__ void gload16(const void* g, const void* l) {
  __builtin_amdgcn_global_load_lds(
      (const __attribute__((address_space(1))) void*)(uintptr_t)g,
      (__attribute__((address_space(3))) void*)(uintptr_t)l, 16, 0, 0);
}

__device__ __forceinline__ float sigf(float x) { return 1.0f / (1.0f + __expf(-x)); }
__device__ __forceinline__ float tanhf_(float x) { return 2.0f / (1.0f + __expf(-2.0f * x)) - 1.0f; }

// ---------------- prep: build interleaved combined weight (bf16) + bias ----------------
// column mapping: n = (u&15) | (g<<4) | ((u>>4)<<6)  ->  orig row r = g*256 + u
__global__ void prep_w(const float* __restrict__ W_ih, const float* __restrict__ W_hh,
                       const float* __restrict__ b_ih, const float* __restrict__ b_hh,
                       __hip_bfloat16* __restrict__ Wc, float* __restrict__ bc) {
  int idx = blockIdx.x * 256 + threadIdx.x;
  if (idx < NG * K_) {
    int n = idx / K_, k = idx % K_;
    int g = (n >> 4) & 3;
    int u = (n & 15) | ((n >> 6) << 4);
    int r = g * H_ + u;
    float v = (k < I_) ? W_ih[r * I_ + k] : W_hh[r * H_ + (k - I_)];
    Wc[idx] = __float2bfloat16(v);
  }
  if (idx < NG) {
    int n = idx;
    int g = (n >> 4) & 3;
    int u = (n & 15) | ((n >> 6) << 4);
    int r = g * H_ + u;
    bc[n] = b_ih[r] + b_hh[r];
  }
}

// ---------------- prep: transpose input_seq [B,L,I] f32 -> xT [L,B,I] bf16 ----------------
__global__ void prep_x(const float* __restrict__ x, __hip_bfloat16* __restrict__ xT) {
  int l = blockIdx.x;
  int b = blockIdx.y * 4 + threadIdx.y;
  int i = threadIdx.x;
  xT[((size_t)l * B_ + b) * I_ + i] = __float2bfloat16(x[((size_t)b * L_ + l) * I_ + i]);
}

// ---------------- prep: zero hA (bf16) and barrier counters ----------------
__global__ void prep_zero(__hip_bfloat16* __restrict__ hA, unsigned int* __restrict__ barct) {
  int idx = blockIdx.x * 256 + threadIdx.x;
  if (idx < B_ * H_) hA[idx] = __float2bfloat16(0.0f);
  if (idx < 32) barct[idx] = 0u;
}

// ---------------- persistent LSTM: all 128 steps, c in regs, group barrier --------------
// grid 256 (cooperative) x 512 threads. 8 waves: wm = wid&3 (rows), wn = wid>>2 (cols).
__global__ __launch_bounds__(512, 2) void lstm_persist(
    const __hip_bfloat16* __restrict__ xT,   // [L][B][64]
    __hip_bfloat16* __restrict__ hA,         // h buffer, even-t input (zeroed)
    __hip_bfloat16* __restrict__ hB,         // h buffer, odd-t input
    const __hip_bfloat16* __restrict__ Wc,   // [1024,320]
    const float* __restrict__ bc,            // [1024]
    unsigned int* __restrict__ barct)        // [32] zeroed
{
  __shared__ __hip_bfloat16 As[2][128 * 64];  // 16KB each, chunk-XOR-swizzled
  __shared__ __hip_bfloat16 Bs[2][128 * 64];

  const int tid = threadIdx.x;
  const int lane = tid & 63;
  const int wid = tid >> 6;       // 0..7
  const int wm = wid & 3;         // row-wave (32 rows)
  const int wn = wid >> 2;        // col-wave (64 cols)

  // XCD-bijective swizzle: 8 n-blocks of a b-group land on one XCD (flat%8).
  const int flat = blockIdx.x;
  const int xcd = flat & 7, slot = flat >> 3;
  const int b_idx = xcd * 4 + (slot >> 3);  // 0..31
  const int n_idx = slot & 7;               // 0..7
  const int b0 = b_idx * 128, n0 = n_idx * 128;
  const int colb = lane & 15;

  // bias per ni (constant across steps)
  float bv4[4];
  #pragma unroll
  for (int ni = 0; ni < 4; ++ni) bv4[ni] = bc[n0 + wn * 64 + ni * 16 + colb];

  // cell state in registers: creg[mi][r] for this lane's 8 (row,u) elements
  float creg[2][4];
  #pragma unroll
  for (int mi = 0; mi < 2; ++mi)
    #pragma unroll
    for (int r = 0; r < 4; ++r) creg[mi][r] = 0.0f;

  const int sr8 = lane >> 3;   // staging row-within-8
  const int sch = lane & 7;    // dest chunk
  const int srcch = sch ^ sr8; // source chunk (XOR involution)

  const int u = 32 * n_idx + 16 * wn + colb;

  #define STAGE(kk, buf, xt, hin)                                                    \
    {                                                                                \
      _Pragma("unroll")                                                              \
      for (int c2 = 0; c2 < 2; ++c2) {                                               \
        const int r = (c2 * 8 + wid) * 8 + sr8;                                      \
        const char* srcA;                                                            \
        if ((kk) == 0)                                                               \
          srcA = (const char*)(xt) + (((size_t)(b0 + r)) * I_ + srcch * 8) * 2;      \
        else                                                                         \
          srcA = (const char*)(hin) +                                                \
                 (((size_t)(b0 + r)) * H_ + ((kk)*64 - 64) + srcch * 8) * 2;         \
        gload16(srcA, (const char*)As[buf] + (c2 * 8 + wid) * 1024);                 \
        const char* srcB = (const char*)Wc +                                         \
                           (((size_t)(n0 + r)) * K_ + (kk)*64 + srcch * 8) * 2;      \
        gload16(srcB, (const char*)Bs[buf] + (c2 * 8 + wid) * 1024);                 \
      }                                                                              \
    }

  for (int t = 0; t < L_; ++t) {
    const __hip_bfloat16* hin = (t & 1) ? hB : hA;
    __hip_bfloat16* hout = (t & 1) ? hA : hB;
    const __hip_bfloat16* xt = xT + (size_t)t * B_ * I_;

    f32x4 acc[2][4];
    #pragma unroll
    for (int ni = 0; ni < 4; ++ni)
      #pragma unroll
      for (int mi = 0; mi < 2; ++mi)
        #pragma unroll
        for (int j = 0; j < 4; ++j) acc[mi][ni][j] = bv4[ni];

    STAGE(0, 0, xt, hin);
    __syncthreads();

    #pragma unroll
    for (int kk = 0; kk < 5; ++kk) {
      const int cur = kk & 1;
      if (kk < 4) STAGE(kk + 1, cur ^ 1, xt, hin);

      const char* Ab = (const char*)As[cur];
      const char* Bb = (const char*)Bs[cur];
      short8 av[2][2], bv[2][4];
      #pragma unroll
      for (int ks = 0; ks < 2; ++ks) {
        const int cc = ks * 4 + (lane >> 4);
        #pragma unroll
        for (int mi = 0; mi < 2; ++mi) {
          const int rr = wm * 32 + mi * 16 + colb;
          av[ks][mi] = *(const short8*)(Ab + rr * 128 + (cc ^ (rr & 7)) * 16);
        }
        #pragma unroll
        for (int ni = 0; ni < 4; ++ni) {
          const int rr = wn * 64 + ni * 16 + colb;
          bv[ks][ni] = *(const short8*)(Bb + rr * 128 + (cc ^ (rr & 7)) * 16);
        }
      }
      #pragma unroll
      for (int ks = 0; ks < 2; ++ks)
        #pragma unroll
        for (int mi = 0; mi < 2; ++mi)
          #pragma unroll
          for (int ni = 0; ni < 4; ++ni)
            acc[mi][ni] = __builtin_amdgcn_mfma_f32_16x16x32_bf16(av[ks][mi], bv[ks][ni],
                                                                  acc[mi][ni], 0, 0, 0);
      __syncthreads();
    }

    // epilogue: ni = gate (i,f,g,o) of unit u; c in regs
    #pragma unroll
    for (int mi = 0; mi < 2; ++mi) {
      #pragma unroll
      for (int r = 0; r < 4; ++r) {
        const int row = b0 + wm * 32 + mi * 16 + (lane >> 4) * 4 + r;
        const float iv = sigf(acc[mi][0][r]);
        const float fv = sigf(acc[mi][1][r]);
        const float gv = tanhf_(acc[mi][2][r]);
        const float ov = sigf(acc[mi][3][r]);
        float cc = fv * creg[mi][r] + iv * gv;
        creg[mi][r] = cc;
        hout[(size_t)row * H_ + u] = __float2bfloat16(ov * tanhf_(cc));
      }
    }

    // group barrier: 8 sibling blocks of this b-group
    __syncthreads();  // all waves' h stores drained (vmcnt0 before s_barrier)
    if (tid == 0) {
      __hip_atomic_fetch_add(barct + b_idx, 1u, __ATOMIC_RELEASE, __HIP_MEMORY_SCOPE_AGENT);
      const unsigned int target = 8u * (unsigned int)(t + 1);
      while (__hip_atomic_load(barct + b_idx, __ATOMIC_ACQUIRE, __HIP_MEMORY_SCOPE_AGENT) <
             target) {
        __builtin_amdgcn_s_sleep(2);
      }
    }
    __syncthreads();
  }
  #undef STAGE
}

// ---------------- hid projections: f_hid/g_hid = hid @ W[:, :256]^T + b ----------------
__global__ __launch_bounds__(256) void hid_proj(
    const __hip_bfloat16* __restrict__ h, const float* __restrict__ drift_W,
    const float* __restrict__ drift_b, const float* __restrict__ diff_W,
    const float* __restrict__ diff_b, float* __restrict__ fhid, float* __restrict__ ghid) {
  __shared__ float WdL[H_ * D_];  // [k][d]
  __shared__ float WgL[H_ * D_];
  for (int idx = threadIdx.x; idx < H_ * D_; idx += 256) {
    int k = idx >> 5, d = idx & 31;
    WdL[idx] = drift_W[d * (H_ + D_) + k];
    WgL[idx] = diff_W[d * (H_ + D_) + k];
  }
  __syncthreads();
  const int row = blockIdx.x * 8 + (threadIdx.x >> 5);
  const int d = threadIdx.x & 31;
  const __hip_bfloat16* hr = h + (size_t)row * H_;
  float f = drift_b[d], g = diff_b[d];
  for (int k = 0; k < H_; ++k) {
    float hv = __bfloat162float(hr[k]);
    f += hv * WdL[k * 32 + d];
    g += hv * WgL[k * 32 + d];
  }
  fhid[(size_t)row * D_ + d] = f;
  ghid[(size_t)row * D_ + d] = g;
}

// ---------------- SDE Euler-Maruyama: LDS row-broadcast, y in regs -------------------
__global__ __launch_bounds__(256) void sde_kernel(
    const float* __restrict__ ts, const float* __restrict__ y0, const float* __restrict__ dW,
    const float* __restrict__ drift_W, const float* __restrict__ diff_W,
    const float* __restrict__ fhid, const float* __restrict__ ghid, float* __restrict__ out) {
  __shared__ float ylds[256];
  const int tid = threadIdx.x;
  const int g = blockIdx.x * 256 + tid;  // b*32+d
  const int d = g & 31;
  const int rb = tid & ~31;  // row base in ylds (32-lane group local)
  float A[32], G[32];
  #pragma unroll
  for (int k = 0; k < 32; ++k) {
    A[k] = drift_W[d * (H_ + D_) + H_ + k];
    G[k] = diff_W[d * (H_ + D_) + H_ + k];
  }
  float y = y0[g];
  const float fh = fhid[g], gh = ghid[g];
  out[g] = y;  // t=0 slice
  float dw0 = dW[g];
  float dw1 = dW[(size_t)(B_ * D_) + g];
  for (int t = 0; t < T_ - 1; ++t) {
    float dwn = 0.0f;
    if (t + 2 < T_ - 1) dwn = dW[(size_t)(t + 2) * (B_ * D_) + g];  // prefetch depth 2
    const float dt = ts[t + 1] - ts[t];
    const float sdt = sqrtf(dt);
    ylds[tid] = y;  // wave-internal broadcast; lgkmcnt ordering by compiler
    float f0 = 0.f, f1 = 0.f, f2 = 0.f, f3 = 0.f;
    float g0 = 0.f, g1 = 0.f, g2 = 0.f, g3 = 0.f;
    #pragma unroll
    for (int c = 0; c < 8; ++c) {
      const f32x4 yv = *(const f32x4*)&ylds[rb + c * 4];
      f0 += A[c * 4 + 0] * yv[0]; g0 += G[c * 4 + 0] * yv[0];
      f1 += A[c * 4 + 1] * yv[1]; g1 += G[c * 4 + 1] * yv[1];
      f2 += A[c * 4 + 2] * yv[2]; g2 += G[c * 4 + 2] * yv[2];
      f3 += A[c * 4 + 3] * yv[3]; g3 += G[c * 4 + 3] * yv[3];
    }
    const float f = fh + ((f0 + f1) + (f2 + f3));
    const float gg = gh + ((g0 + g1) + (g2 + g3));
    y = y + f * dt + gg * (dw0 * sdt);
    out[(size_t)(t + 1) * (B_ * D_) + g] = y;
    dw0 = dw1;
    dw1 = dwn;
  }
}

extern "C" void kernel_launch(void* const* d_in, const int* in_sizes, int n_in,
                              void* d_out, int out_size, void* d_ws, size_t ws_size,
                              hipStream_t stream) {
  const float* ts = (const float*)d_in[0];
  const float* y0 = (const float*)d_in[1];
  const float* xseq = (const float*)d_in[2];
  const float* dW = (const float*)d_in[3];
  const float* W_ih = (const float*)d_in[4];
  const float* W_hh = (const float*)d_in[5];
  const float* b_ih = (const float*)d_in[6];
  const float* b_hh = (const float*)d_in[7];
  const float* drift_W = (const float*)d_in[8];
  const float* drift_b = (const float*)d_in[9];
  const float* diff_W = (const float*)d_in[10];
  const float* diff_b = (const float*)d_in[11];
  float* out = (float*)d_out;

  char* p = (char*)d_ws;
  __hip_bfloat16* xT = (__hip_bfloat16*)p; p += (size_t)L_ * B_ * I_ * 2;  // 67.1 MB
  __hip_bfloat16* Wc = (__hip_bfloat16*)p; p += (size_t)NG * K_ * 2;       // 655 KB
  float* bc = (float*)p;                   p += (size_t)NG * 4;
  __hip_bfloat16* hA = (__hip_bfloat16*)p; p += (size_t)B_ * H_ * 2;
  __hip_bfloat16* hB = (__hip_bfloat16*)p; p += (size_t)B_ * H_ * 2;
  float* fh = (float*)p;                   p += (size_t)B_ * D_ * 4;
  float* gh = (float*)p;                   p += (size_t)B_ * D_ * 4;
  unsigned int* barct = (unsigned int*)p;  p += 32 * 4;

  prep_w<<<(NG * K_ + 255) / 256, 256, 0, stream>>>(W_ih, W_hh, b_ih, b_hh, Wc, bc);
  prep_x<<<dim3(L_, B_ / 4), dim3(64, 4), 0, stream>>>(xseq, xT);
  prep_zero<<<(B_ * H_ + 255) / 256, 256, 0, stream>>>(hA, barct);

  {
    const __hip_bfloat16* xT_c = xT;
    const __hip_bfloat16* Wc_c = Wc;
    const float* bc_c = bc;
    void* args[] = {(void*)&xT_c, (void*)&hA, (void*)&hB, (void*)&Wc_c, (void*)&bc_c,
                    (void*)&barct};
    hipLaunchCooperativeKernel(reinterpret_cast<void*>(lstm_persist), dim3(256), dim3(512),
                               args, 0, stream);
  }

  // after 128 steps (even count), final hidden state is in hA
  hid_proj<<<B_ / 8, 256, 0, stream>>>(hA, drift_W, drift_b, diff_W, diff_b, fh, gh);
  sde_kernel<<<(B_ * D_) / 256, 256, 0, stream>>>(ts, y0, dW, drift_W, diff_W, fh, gh, out);
}

// Round 7
// 2144.240 us; speedup vs baseline: 1.1356x; 1.1356x over previous
//
#include <hip/hip_runtime.h>
#include <hip/hip_bf16.h>
#include <stdint.h>

#define B_ 4096
#define L_ 128
#define I_ 64
#define H_ 256
#define D_ 32
#define T_ 101
#define K_ 320   // I_+H_
#define NG 1024  // 4*H_
#define HD 288   // H_+D_

typedef __attribute__((ext_vector_type(8))) short short8;
typedef __attribute__((ext_vector_type(4))) float f32x4;

__device__ __forceinline__ float sigf(float x) { return 1.0f / (1.0f + __expf(-x)); }
__device__ __forceinline__ float tanhf_(float x) { return 2.0f / (1.0f + __expf(-2.0f * x)) - 1.0f; }
__device__ __forceinline__ float bf16bits_to_f(unsigned short us) {
  union { unsigned int u; float f; } cv;
  cv.u = ((unsigned int)us) << 16;
  return cv.f;
}

// ---------------- prep: build interleaved combined weight (bf16) + bias ----------------
// column mapping: n = (u&15) | (gate<<4) | ((u>>4)<<6)  ->  orig row r = gate*256 + u
__global__ void prep_w(const float* __restrict__ W_ih, const float* __restrict__ W_hh,
                       const float* __restrict__ b_ih, const float* __restrict__ b_hh,
                       __hip_bfloat16* __restrict__ Wc, float* __restrict__ bc) {
  int idx = blockIdx.x * 256 + threadIdx.x;
  if (idx < NG * K_) {
    int n = idx / K_, k = idx % K_;
    int g = (n >> 4) & 3;
    int u = (n & 15) | ((n >> 6) << 4);
    int r = g * H_ + u;
    float v = (k < I_) ? W_ih[r * I_ + k] : W_hh[r * H_ + (k - I_)];
    Wc[idx] = __float2bfloat16(v);
  }
  if (idx < NG) {
    int n = idx;
    int g = (n >> 4) & 3;
    int u = (n & 15) | ((n >> 6) << 4);
    int r = g * H_ + u;
    bc[n] = b_ih[r] + b_hh[r];
  }
}

// ---------------- fused LSTM: one block = 16 rows x ALL gates; weights in VGPRs --------
// 256 blocks x 1024 threads (16 waves). Wave wn owns gate-cols [wn*64, wn*64+64).
// h lives in LDS (double-buffered, 16B-slot XOR swizzle); c in registers; ONE
// __syncthreads per step; zero inter-block traffic.
__global__ __launch_bounds__(1024) void lstm_fused(
    const float* __restrict__ xseq,          // [B][L][64] f32 (original layout)
    const __hip_bfloat16* __restrict__ Wc,   // [1024][320] interleaved
    const float* __restrict__ bc,            // [1024]
    __hip_bfloat16* __restrict__ hA)         // [B][256] final hidden out
{
  __shared__ __align__(16) __hip_bfloat16 xs[2][16 * 64];   // 2 KB each, swizzled slots
  __shared__ __align__(16) __hip_bfloat16 hs[2][16 * 256];  // 8 KB each, swizzled slots

  const int tid = threadIdx.x;
  const int lane = tid & 63;
  const int wn = tid >> 6;       // wave 0..15 -> gate-cols [wn*64, +64)
  const int colb = lane & 15;
  const int g4 = lane >> 4;      // 0..3
  const int b0 = blockIdx.x * 16;

  // B fragments resident in registers: 10 k-chunks x 4 ni = 160 VGPR
  short8 bv[10][4];
  #pragma unroll
  for (int ks = 0; ks < 10; ++ks)
    #pragma unroll
    for (int ni = 0; ni < 4; ++ni) {
      const int n = wn * 64 + ni * 16 + colb;
      bv[ks][ni] = *(const short8*)((const char*)Wc + (((size_t)n) * K_ + ks * 32 + g4 * 8) * 2);
    }
  float bv4[4];
  #pragma unroll
  for (int ni = 0; ni < 4; ++ni) bv4[ni] = bc[wn * 64 + ni * 16 + colb];

  float creg[4] = {0.f, 0.f, 0.f, 0.f};
  const int u = wn * 16 + colb;  // unit owned by this lane

  // x staging role: thread -> (row xr, k xk); swizzled dest byte offset
  const int xr = tid >> 6;
  const int xk = tid & 63;
  const int xdst = xr * 128 + (((xk >> 3) ^ (xr & 7)) * 16) + (xk & 7) * 2;

  // prologue: zero hs[0] (h(0)=0), stage x(0)
  if (tid < 512) *(f32x4*)((char*)hs[0] + tid * 16) = f32x4{0.f, 0.f, 0.f, 0.f};
  {
    const float xv = xseq[((size_t)(b0 + xr) * L_ + 0) * I_ + xk];
    *(__hip_bfloat16*)((char*)xs[0] + xdst) = __float2bfloat16(xv);
  }
  __syncthreads();

  for (int t = 0; t < L_; ++t) {
    const int cb = t & 1;
    // issue next x load early (latency hides under MFMA phase)
    float xnext = 0.f;
    if (t + 1 < L_) xnext = xseq[((size_t)(b0 + xr) * L_ + (t + 1)) * I_ + xk];

    f32x4 acc[4];
    #pragma unroll
    for (int ni = 0; ni < 4; ++ni) {
      acc[ni][0] = bv4[ni]; acc[ni][1] = bv4[ni];
      acc[ni][2] = bv4[ni]; acc[ni][3] = bv4[ni];
    }

    const char* xb = (const char*)xs[cb];
    const char* hb = (const char*)hs[cb];
    #pragma unroll
    for (int ks = 0; ks < 10; ++ks) {
      short8 av;
      if (ks < 2) {  // x part: row stride 128 B, 8 slots
        const int w = (ks * 4 + g4) ^ (colb & 7);
        av = *(const short8*)(xb + colb * 128 + w * 16);
      } else {       // h part: row stride 512 B, 32 slots, XOR low-3 bits
        const int w = ((ks - 2) * 4 + g4) ^ (colb & 7);
        av = *(const short8*)(hb + colb * 512 + w * 16);
      }
      #pragma unroll
      for (int ni = 0; ni < 4; ++ni)
        acc[ni] = __builtin_amdgcn_mfma_f32_16x16x32_bf16(av, bv[ks][ni], acc[ni], 0, 0, 0);
    }

    // epilogue: ni = gate (i,f,g,o) of unit u; c in regs; h -> LDS (or global at last step)
    char* ho = (char*)hs[cb ^ 1];
    #pragma unroll
    for (int r = 0; r < 4; ++r) {
      const int row = g4 * 4 + r;
      const float iv = sigf(acc[0][r]);
      const float fv = sigf(acc[1][r]);
      const float gv = tanhf_(acc[2][r]);
      const float ov = sigf(acc[3][r]);
      const float cc = fv * creg[r] + iv * gv;
      creg[r] = cc;
      const __hip_bfloat16 hv = __float2bfloat16(ov * tanhf_(cc));
      if (t < L_ - 1) {
        const int slot = (u >> 3) ^ (row & 7);
        *(__hip_bfloat16*)(ho + row * 512 + slot * 16 + (u & 7) * 2) = hv;
      } else {
        hA[(size_t)(b0 + row) * H_ + u] = hv;
      }
    }
    // write next x tile (buffer not read until after the barrier)
    if (t + 1 < L_) {
      *(__hip_bfloat16*)((char*)xs[cb ^ 1] + xdst) = __float2bfloat16(xnext);
    }
    __syncthreads();
  }
}

// ---------------- SDE: fused hid-projection + Euler-Maruyama, depth-4 dW prefetch ------
__global__ __launch_bounds__(256) void sde2(
    const float* __restrict__ ts, const float* __restrict__ y0, const float* __restrict__ dW,
    const float* __restrict__ drift_W, const float* __restrict__ drift_b,
    const float* __restrict__ diff_W, const float* __restrict__ diff_b,
    const __hip_bfloat16* __restrict__ hA, float* __restrict__ out) {
  __shared__ float WdL[H_ * D_];  // [k][d] transposed, 32 KB
  __shared__ float WgL[H_ * D_];  // 32 KB
  const int tid = threadIdx.x;
  for (int idx = tid; idx < H_ * D_; idx += 256) {
    const int k = idx >> 5, d = idx & 31;
    WdL[idx] = drift_W[d * HD + k];
    WgL[idx] = diff_W[d * HD + k];
  }
  __syncthreads();

  const int gix = blockIdx.x * 256 + tid;  // row*32 + d
  const int d = tid & 31;
  const int row = gix >> 5;
  const int rb = tid & ~31;

  float A[32], G[32];
  #pragma unroll
  for (int k = 0; k < 32; ++k) {
    A[k] = drift_W[d * HD + H_ + k];
    G[k] = diff_W[d * HD + H_ + k];
  }

  // inline hid projection: fh/gh = hid @ W[:, :256]^T + b
  float fhv = drift_b[d], ghv = diff_b[d];
  {
    const __hip_bfloat16* hr = hA + (size_t)row * H_;
    #pragma unroll 4
    for (int c = 0; c < 32; ++c) {
      const short8 hx = *(const short8*)(hr + c * 8);
      #pragma unroll
      for (int j = 0; j < 8; ++j) {
        const float hv = bf16bits_to_f((unsigned short)hx[j]);
        fhv += hv * WdL[(c * 8 + j) * 32 + d];
        ghv += hv * WgL[(c * 8 + j) * 32 + d];
      }
    }
  }

  __shared__ float ylds[256];
  float y = y0[gix];
  out[gix] = y;  // t=0 slice

  // depth-4 dW prefetch ring (static indices via 4x unroll)
  float dw[4];
  #pragma unroll
  for (int i = 0; i < 4; ++i) dw[i] = dW[(size_t)i * (B_ * D_) + gix];

  for (int t = 0; t < T_ - 1; t += 4) {
    #pragma unroll
    for (int j = 0; j < 4; ++j) {
      const int tt = t + j;
      const float dt = ts[tt + 1] - ts[tt];
      const float sdt = sqrtf(dt);
      ylds[tid] = y;  // wave-internal broadcast (32-lane group), lgkm-ordered
      float f0 = 0.f, f1 = 0.f, f2 = 0.f, f3 = 0.f;
      float g0 = 0.f, g1 = 0.f, g2 = 0.f, g3 = 0.f;
      #pragma unroll
      for (int c = 0; c < 8; ++c) {
        const f32x4 yv = *(const f32x4*)&ylds[rb + c * 4];
        f0 += A[c * 4 + 0] * yv[0]; g0 += G[c * 4 + 0] * yv[0];
        f1 += A[c * 4 + 1] * yv[1]; g1 += G[c * 4 + 1] * yv[1];
        f2 += A[c * 4 + 2] * yv[2]; g2 += G[c * 4 + 2] * yv[2];
        f3 += A[c * 4 + 3] * yv[3]; g3 += G[c * 4 + 3] * yv[3];
      }
      const float f = fhv + ((f0 + f1) + (f2 + f3));
      const float gg = ghv + ((g0 + g1) + (g2 + g3));
      y = y + f * dt + gg * (dw[j] * sdt);
      out[(size_t)(tt + 1) * (B_ * D_) + gix] = y;
      const int tn = tt + 4;
      dw[j] = (tn < T_ - 1) ? dW[(size_t)tn * (B_ * D_) + gix] : 0.0f;
    }
  }
}

extern "C" void kernel_launch(void* const* d_in, const int* in_sizes, int n_in,
                              void* d_out, int out_size, void* d_ws, size_t ws_size,
                              hipStream_t stream) {
  const float* ts = (const float*)d_in[0];
  const float* y0 = (const float*)d_in[1];
  const float* xseq = (const float*)d_in[2];
  const float* dW = (const float*)d_in[3];
  const float* W_ih = (const float*)d_in[4];
  const float* W_hh = (const float*)d_in[5];
  const float* b_ih = (const float*)d_in[6];
  const float* b_hh = (const float*)d_in[7];
  const float* drift_W = (const float*)d_in[8];
  const float* drift_b = (const float*)d_in[9];
  const float* diff_W = (const float*)d_in[10];
  const float* diff_b = (const float*)d_in[11];
  float* out = (float*)d_out;

  char* p = (char*)d_ws;
  __hip_bfloat16* Wc = (__hip_bfloat16*)p; p += (size_t)NG * K_ * 2;  // 655 KB
  float* bc = (float*)p;                   p += (size_t)NG * 4;
  __hip_bfloat16* hA = (__hip_bfloat16*)p; p += (size_t)B_ * H_ * 2;  // 2 MB

  prep_w<<<(NG * K_ + 255) / 256, 256, 0, stream>>>(W_ih, W_hh, b_ih, b_hh, Wc, bc);
  lstm_fused<<<B_ / 16, 1024, 0, stream>>>(xseq, Wc, bc, hA);
  sde2<<<(B_ * D_) / 256, 256, 0, stream>>>(ts, y0, dW, drift_W, drift_b, diff_W, diff_b,
                                            hA, out);
}